// Round 7
// baseline (807.571 us; speedup 1.0000x reference)
//
#include <hip/hip_runtime.h>

#define D_IN  128
#define D_HID 64
#define D_OUT 40

// ---- degree count + edge rank (self-loop +1 folded into k_dinv) ----
// atomicAdd's return value IS the edge's slot within its dst segment.
__global__ __launch_bounds__(256) void k_deg(const int* __restrict__ dst,
                                             unsigned int* __restrict__ cnt,
                                             unsigned int* __restrict__ rank, int E) {
    int e = blockIdx.x * 256 + threadIdx.x;
    if (e < E) rank[e] = atomicAdd(&cnt[dst[e]], 1u);
}

__global__ __launch_bounds__(256) void k_dinv(const unsigned int* __restrict__ deg,
                                              float* __restrict__ dinv, int N) {
    int i = blockIdx.x * 256 + threadIdx.x;
    if (i < N) dinv[i] = rsqrtf((float)(deg[i] + 1u));
}

// ---- exclusive scan of deg -> offsets (3-kernel hierarchical) ----
__global__ __launch_bounds__(256) void k_scan1(const unsigned int* __restrict__ deg,
                                               unsigned int* __restrict__ off,
                                               unsigned int* __restrict__ bsum, int N) {
    __shared__ unsigned int s[256];
    const int tid = threadIdx.x;
    const int i = blockIdx.x * 256 + tid;
    unsigned int v = (i < N) ? deg[i] : 0u;
    s[tid] = v;
    __syncthreads();
    for (int d = 1; d < 256; d <<= 1) {
        unsigned int t = (tid >= d) ? s[tid - d] : 0u;
        __syncthreads();
        s[tid] += t;
        __syncthreads();
    }
    if (i < N) off[i] = s[tid] - v;              // exclusive
    if (tid == 255) bsum[blockIdx.x] = s[tid];   // block total
}

__global__ __launch_bounds__(512) void k_scan2(unsigned int* __restrict__ bsum, int NB) {
    __shared__ unsigned int s[512];
    const int tid = threadIdx.x;
    unsigned int v = (tid < NB) ? bsum[tid] : 0u;
    s[tid] = v;
    __syncthreads();
    for (int d = 1; d < 512; d <<= 1) {
        unsigned int t = (tid >= d) ? s[tid - d] : 0u;
        __syncthreads();
        s[tid] += t;
        __syncthreads();
    }
    if (tid < NB) bsum[tid] = s[tid] - v;        // exclusive over block sums
}

__global__ __launch_bounds__(256) void k_scan3(unsigned int* __restrict__ off,
                                               const unsigned int* __restrict__ bsum,
                                               int N, int E) {
    int i = blockIdx.x * 256 + threadIdx.x;
    if (i < N) off[i] += bsum[blockIdx.x];
    if (i == 0) off[N] = (unsigned int)E;
}

// ---- atomic-free counting-sort fill: csr_src[off[dst]+rank] = src ----
__global__ __launch_bounds__(256) void k_fill(const int* __restrict__ src,
                                              const int* __restrict__ dst,
                                              const unsigned int* __restrict__ off,
                                              const unsigned int* __restrict__ rank,
                                              int* __restrict__ csr_src, int E) {
    int e = blockIdx.x * 256 + threadIdx.x;
    if (e >= E) return;
    csr_src[off[dst[e]] + rank[e]] = src[e];
}

// ---- h1s = (x @ W1) * dinv[row] ; 16 rows/block, 4 accs/thread ----
__global__ __launch_bounds__(256) void k_gemm1(const float* __restrict__ x,
                                               const float* __restrict__ W1,
                                               const float* __restrict__ dinv,
                                               float* __restrict__ h1s, int N) {
    __shared__ float w[D_IN * D_HID];   // 32 KB
    __shared__ float xs[16 * D_IN];     // 8 KB
    const int tid = threadIdx.x;
    for (int i = tid; i < D_IN * D_HID; i += 256) w[i] = W1[i];
    const int row0 = blockIdx.x * 16;
    for (int i = tid; i < 16 * D_IN; i += 256) {
        int r = row0 + (i >> 7);
        xs[i] = (r < N) ? x[(size_t)row0 * D_IN + i] : 0.0f;
    }
    __syncthreads();
    const int col = tid & 63;
    const int rg  = tid >> 6;            // wave id 0..3 -> rows rg*4 .. rg*4+3
    float a0 = 0, a1 = 0, a2 = 0, a3 = 0;
#pragma unroll
    for (int k = 0; k < D_IN; ++k) {
        float wv = w[k * D_HID + col];
        a0 = fmaf(xs[(rg * 4 + 0) * D_IN + k], wv, a0);
        a1 = fmaf(xs[(rg * 4 + 1) * D_IN + k], wv, a1);
        a2 = fmaf(xs[(rg * 4 + 2) * D_IN + k], wv, a2);
        a3 = fmaf(xs[(rg * 4 + 3) * D_IN + k], wv, a3);
    }
    float acc[4] = {a0, a1, a2, a3};
#pragma unroll
    for (int i = 0; i < 4; ++i) {
        int row = row0 + rg * 4 + i;
        if (row < N) h1s[(size_t)row * D_HID + col] = acc[i] * dinv[row];
    }
}

// ---- h2s = (hidden @ W2) * dinv[row] ; 16 rows/block, 2 accs/thread ----
__global__ __launch_bounds__(320) void k_gemm2(const float* __restrict__ hid,
                                               const float* __restrict__ W2,
                                               const float* __restrict__ dinv,
                                               float* __restrict__ h2s, int N) {
    __shared__ float w[D_HID * D_OUT];  // 10 KB
    __shared__ float xs[16 * D_HID];    // 4 KB
    const int tid = threadIdx.x;
    for (int i = tid; i < D_HID * D_OUT; i += 320) w[i] = W2[i];
    const int row0 = blockIdx.x * 16;
    for (int i = tid; i < 16 * D_HID; i += 320) {
        int r = row0 + (i >> 6);
        xs[i] = (r < N) ? hid[(size_t)row0 * D_HID + i] : 0.0f;
    }
    __syncthreads();
    const int col = tid % D_OUT;
    const int rq  = tid / D_OUT;        // 0..7 -> rows rq and rq+8
    float a0 = 0, a1 = 0;
#pragma unroll
    for (int k = 0; k < D_HID; ++k) {
        float wv = w[k * D_OUT + col];
        a0 = fmaf(xs[rq * D_HID + k], wv, a0);
        a1 = fmaf(xs[(rq + 8) * D_HID + k], wv, a1);
    }
    int r0 = row0 + rq, r1 = row0 + rq + 8;
    if (r0 < N) h2s[(size_t)r0 * D_OUT + col] = a0 * dinv[r0];
    if (r1 < N) h2s[(size_t)r1 * D_OUT + col] = a1 * dinv[r1];
}

// ---- gather1: hidden[n] = relu(dinv[n]*(Σ_in h1s[src] + h1s[n]) + b1) ----
// one wave per node; lane = col. 4 independent row-loads in flight.
__global__ __launch_bounds__(256) void k_gather1(const unsigned int* __restrict__ off,
                                                 const int* __restrict__ csr_src,
                                                 const float* __restrict__ h1s,
                                                 const float* __restrict__ dinv,
                                                 const float* __restrict__ b1,
                                                 float* __restrict__ hidden, int N) {
    const int wid  = (blockIdx.x * 256 + threadIdx.x) >> 6;
    const int lane = threadIdx.x & 63;
    if (wid >= N) return;
    const int start = (int)off[wid];
    const int end   = (int)off[wid + 1];
    float acc = h1s[(size_t)wid * D_HID + lane];   // self-loop term
    for (int base = start; base < end; base += 64) {
        const int nb = min(64, end - base);
        int sv = (base + lane < end) ? csr_src[base + lane] : 0;
        int j = 0;
        for (; j + 3 < nb; j += 4) {
            int s0 = __shfl(sv, j),     s1 = __shfl(sv, j + 1);
            int s2 = __shfl(sv, j + 2), s3 = __shfl(sv, j + 3);
            float v0 = h1s[(size_t)s0 * D_HID + lane];
            float v1 = h1s[(size_t)s1 * D_HID + lane];
            float v2 = h1s[(size_t)s2 * D_HID + lane];
            float v3 = h1s[(size_t)s3 * D_HID + lane];
            acc += (v0 + v1) + (v2 + v3);
        }
        for (; j < nb; ++j) {
            int s = __shfl(sv, j);
            acc += h1s[(size_t)s * D_HID + lane];
        }
    }
    float v = dinv[wid] * acc + b1[lane];
    hidden[(size_t)wid * D_HID + lane] = v > 0.0f ? v : 0.0f;
}

// ---- gather2: out[n] = dinv[n]*(Σ_in h2s[src] + h2s[n]) + b2 ----
__global__ __launch_bounds__(256) void k_gather2(const unsigned int* __restrict__ off,
                                                 const int* __restrict__ csr_src,
                                                 const float* __restrict__ h2s,
                                                 const float* __restrict__ dinv,
                                                 const float* __restrict__ b2,
                                                 float* __restrict__ out, int N) {
    const int wid  = (blockIdx.x * 256 + threadIdx.x) >> 6;
    const int lane = threadIdx.x & 63;
    if (wid >= N) return;
    const int start = (int)off[wid];
    const int end   = (int)off[wid + 1];
    const bool act = lane < D_OUT;
    float acc = act ? h2s[(size_t)wid * D_OUT + lane] : 0.0f;
    for (int base = start; base < end; base += 64) {
        const int nb = min(64, end - base);
        int sv = (base + lane < end) ? csr_src[base + lane] : 0;
        int j = 0;
        for (; j + 3 < nb; j += 4) {
            int s0 = __shfl(sv, j),     s1 = __shfl(sv, j + 1);
            int s2 = __shfl(sv, j + 2), s3 = __shfl(sv, j + 3);
            if (act) {
                float v0 = h2s[(size_t)s0 * D_OUT + lane];
                float v1 = h2s[(size_t)s1 * D_OUT + lane];
                float v2 = h2s[(size_t)s2 * D_OUT + lane];
                float v3 = h2s[(size_t)s3 * D_OUT + lane];
                acc += (v0 + v1) + (v2 + v3);
            }
        }
        for (; j < nb; ++j) {
            int s = __shfl(sv, j);
            if (act) acc += h2s[(size_t)s * D_OUT + lane];
        }
    }
    if (act) out[(size_t)wid * D_OUT + lane] = dinv[wid] * acc + b2[lane];
}

extern "C" void kernel_launch(void* const* d_in, const int* in_sizes, int n_in,
                              void* d_out, int out_size, void* d_ws, size_t ws_size,
                              hipStream_t stream) {
    const float* x  = (const float*)d_in[0];
    const int*  eix = (const int*)d_in[1];   // [2, E] int32 per harness contract
    const float* W1 = (const float*)d_in[2];
    const float* b1 = (const float*)d_in[3];
    const float* W2 = (const float*)d_in[4];
    const float* b2 = (const float*)d_in[5];
    float* out = (float*)d_out;

    const int N = in_sizes[0] / D_IN;
    const int E = in_sizes[1] / 2;
    const int* src = eix;
    const int* dst = eix + E;
    const int NB = (N + 255) / 256;   // scan blocks (<=512 required by k_scan2)

    // workspace layout: deg | dinv | offsets(N+1) | bsums(512) | csr_src(E) | h1s | hidden
    // rank aliases hidden (hidden first written by gather1, after fill consumed rank).
    // h2s aliases h1s (h1s dead after gather1).
    char* ws = (char*)d_ws;
    size_t off_b = 0;
    auto alloc = [&](size_t bytes) {
        void* p = ws + off_b;
        off_b = (off_b + bytes + 255) & ~(size_t)255;
        return p;
    };
    unsigned int* deg     = (unsigned int*)alloc((size_t)N * 4);
    float*        dinv    = (float*)alloc((size_t)N * 4);
    unsigned int* offsets = (unsigned int*)alloc((size_t)(N + 1) * 4);
    unsigned int* bsums   = (unsigned int*)alloc(512 * 4);
    int*          csr_src = (int*)alloc((size_t)E * 4);
    float*        h1s     = (float*)alloc((size_t)N * D_HID * 4);
    float*        hidden  = (float*)alloc((size_t)N * D_HID * 4);
    float*        h2s     = h1s;                    // alias: h1s dead after gather1
    unsigned int* rank    = (unsigned int*)hidden;  // alias: rank dead before gather1 writes hidden

    hipMemsetAsync(deg, 0, (size_t)N * 4, stream);

    // CSR build (atomic-free fill via rank trick)
    k_deg  <<<(E + 255) / 256, 256, 0, stream>>>(dst, deg, rank, E);
    k_dinv <<<NB, 256, 0, stream>>>(deg, dinv, N);
    k_scan1<<<NB, 256, 0, stream>>>(deg, offsets, bsums, N);
    k_scan2<<<1, 512, 0, stream>>>(bsums, NB);
    k_scan3<<<NB, 256, 0, stream>>>(offsets, bsums, N, E);
    k_fill <<<(E + 255) / 256, 256, 0, stream>>>(src, dst, offsets, rank, csr_src, E);

    // layer 1
    k_gemm1  <<<(N + 15) / 16, 256, 0, stream>>>(x, W1, dinv, h1s, N);
    k_gather1<<<(N + 3) / 4, 256, 0, stream>>>(offsets, csr_src, h1s, dinv, b1, hidden, N);

    // layer 2
    k_gemm2  <<<(N + 15) / 16, 320, 0, stream>>>(hidden, W2, dinv, h2s, N);
    k_gather2<<<(N + 3) / 4, 256, 0, stream>>>(offsets, csr_src, h2s, dinv, b2, out, N);
}

// Round 8
// 452.756 us; speedup vs baseline: 1.7837x; 1.7837x over previous
//
#include <hip/hip_runtime.h>

#define D_IN  128
#define D_HID 64
#define D_OUT 40

// ---- degree count + edge rank (self-loop +1 folded into k_dinv) ----
// atomicAdd's return value IS the edge's slot within its dst segment.
__global__ __launch_bounds__(256) void k_deg(const int* __restrict__ dst,
                                             unsigned int* __restrict__ cnt,
                                             unsigned int* __restrict__ rank, int E) {
    int e = blockIdx.x * 256 + threadIdx.x;
    if (e < E) rank[e] = atomicAdd(&cnt[dst[e]], 1u);
}

__global__ __launch_bounds__(256) void k_dinv(const unsigned int* __restrict__ deg,
                                              float* __restrict__ dinv, int N) {
    int i = blockIdx.x * 256 + threadIdx.x;
    if (i < N) dinv[i] = rsqrtf((float)(deg[i] + 1u));
}

// ---- exclusive scan of deg -> offsets (3-kernel hierarchical) ----
__global__ __launch_bounds__(256) void k_scan1(const unsigned int* __restrict__ deg,
                                               unsigned int* __restrict__ off,
                                               unsigned int* __restrict__ bsum, int N) {
    __shared__ unsigned int s[256];
    const int tid = threadIdx.x;
    const int i = blockIdx.x * 256 + tid;
    unsigned int v = (i < N) ? deg[i] : 0u;
    s[tid] = v;
    __syncthreads();
    for (int d = 1; d < 256; d <<= 1) {
        unsigned int t = (tid >= d) ? s[tid - d] : 0u;
        __syncthreads();
        s[tid] += t;
        __syncthreads();
    }
    if (i < N) off[i] = s[tid] - v;              // exclusive
    if (tid == 255) bsum[blockIdx.x] = s[tid];   // block total
}

__global__ __launch_bounds__(512) void k_scan2(unsigned int* __restrict__ bsum, int NB) {
    __shared__ unsigned int s[512];
    const int tid = threadIdx.x;
    unsigned int v = (tid < NB) ? bsum[tid] : 0u;
    s[tid] = v;
    __syncthreads();
    for (int d = 1; d < 512; d <<= 1) {
        unsigned int t = (tid >= d) ? s[tid - d] : 0u;
        __syncthreads();
        s[tid] += t;
        __syncthreads();
    }
    if (tid < NB) bsum[tid] = s[tid] - v;        // exclusive over block sums
}

__global__ __launch_bounds__(256) void k_scan3(unsigned int* __restrict__ off,
                                               const unsigned int* __restrict__ bsum,
                                               int N, int E) {
    int i = blockIdx.x * 256 + threadIdx.x;
    if (i < N) off[i] += bsum[blockIdx.x];
    if (i == 0) off[N] = (unsigned int)E;
}

// ---- atomic-free counting-sort fill: csr_src[off[dst]+rank] = src ----
__global__ __launch_bounds__(256) void k_fill(const int* __restrict__ src,
                                              const int* __restrict__ dst,
                                              const unsigned int* __restrict__ off,
                                              const unsigned int* __restrict__ rank,
                                              int* __restrict__ csr_src, int E) {
    int e = blockIdx.x * 256 + threadIdx.x;
    if (e >= E) return;
    csr_src[off[dst[e]] + rank[e]] = src[e];
}

// ---- h1s = (x @ W1) * dinv[row] ; 4 rows/block, 1 acc/thread (no-spill shape) ----
__global__ __launch_bounds__(256) void k_gemm1(const float* __restrict__ x,
                                               const float* __restrict__ W1,
                                               const float* __restrict__ dinv,
                                               float* __restrict__ h1s, int N) {
    __shared__ float w[D_IN * D_HID];   // 32 KB
    __shared__ float xs[4 * D_IN];      // 2 KB
    const int tid = threadIdx.x;
    for (int i = tid; i < D_IN * D_HID; i += 256) w[i] = W1[i];
    const int row0 = blockIdx.x * 4;
    for (int i = tid; i < 4 * D_IN; i += 256) {
        int r = row0 + (i >> 7);
        xs[i] = (r < N) ? x[(size_t)row0 * D_IN + i] : 0.0f;
    }
    __syncthreads();
    const int col = tid & 63;
    const int r   = tid >> 6;
    const int row = row0 + r;
    float sum = 0.0f;
#pragma unroll
    for (int k = 0; k < D_IN; ++k)
        sum = fmaf(xs[r * D_IN + k], w[k * D_HID + col], sum);
    if (row < N) h1s[(size_t)row * D_HID + col] = sum * dinv[row];
}

// ---- h2s = (hidden @ W2) * dinv[row] ; 8 rows/block, 1 acc/thread ----
__global__ __launch_bounds__(320) void k_gemm2(const float* __restrict__ hid,
                                               const float* __restrict__ W2,
                                               const float* __restrict__ dinv,
                                               float* __restrict__ h2s, int N) {
    __shared__ float w[D_HID * D_OUT];  // 10 KB
    __shared__ float xs[8 * D_HID];     // 2 KB
    const int tid = threadIdx.x;
    for (int i = tid; i < D_HID * D_OUT; i += 320) w[i] = W2[i];
    const int row0 = blockIdx.x * 8;
    for (int i = tid; i < 8 * D_HID; i += 320) {
        int r = row0 + (i >> 6);
        xs[i] = (r < N) ? hid[(size_t)row0 * D_HID + i] : 0.0f;
    }
    __syncthreads();
    const int col = tid % D_OUT;
    const int r   = tid / D_OUT;
    const int row = row0 + r;
    float sum = 0.0f;
#pragma unroll
    for (int k = 0; k < D_HID; ++k)
        sum = fmaf(xs[r * D_HID + k], w[k * D_OUT + col], sum);
    if (row < N) h2s[(size_t)row * D_OUT + col] = sum * dinv[row];
}

// ---- gather1: hidden[n] = relu(dinv[n]*(Σ_in h1s[src] + h1s[n]) + b1) ----
// one wave per node; lane = col. 4 independent row-loads in flight.
__global__ __launch_bounds__(256) void k_gather1(const unsigned int* __restrict__ off,
                                                 const int* __restrict__ csr_src,
                                                 const float* __restrict__ h1s,
                                                 const float* __restrict__ dinv,
                                                 const float* __restrict__ b1,
                                                 float* __restrict__ hidden, int N) {
    const int wid  = (blockIdx.x * 256 + threadIdx.x) >> 6;
    const int lane = threadIdx.x & 63;
    if (wid >= N) return;
    const int start = (int)off[wid];
    const int end   = (int)off[wid + 1];
    float acc = h1s[(size_t)wid * D_HID + lane];   // self-loop term
    for (int base = start; base < end; base += 64) {
        const int nb = min(64, end - base);
        int sv = (base + lane < end) ? csr_src[base + lane] : 0;
        int j = 0;
        for (; j + 3 < nb; j += 4) {
            int s0 = __shfl(sv, j),     s1 = __shfl(sv, j + 1);
            int s2 = __shfl(sv, j + 2), s3 = __shfl(sv, j + 3);
            float v0 = h1s[(size_t)s0 * D_HID + lane];
            float v1 = h1s[(size_t)s1 * D_HID + lane];
            float v2 = h1s[(size_t)s2 * D_HID + lane];
            float v3 = h1s[(size_t)s3 * D_HID + lane];
            acc += (v0 + v1) + (v2 + v3);
        }
        for (; j < nb; ++j) {
            int s = __shfl(sv, j);
            acc += h1s[(size_t)s * D_HID + lane];
        }
    }
    float v = dinv[wid] * acc + b1[lane];
    hidden[(size_t)wid * D_HID + lane] = v > 0.0f ? v : 0.0f;
}

// ---- gather2: out[n] = dinv[n]*(Σ_in h2s[src] + h2s[n]) + b2 ----
__global__ __launch_bounds__(256) void k_gather2(const unsigned int* __restrict__ off,
                                                 const int* __restrict__ csr_src,
                                                 const float* __restrict__ h2s,
                                                 const float* __restrict__ dinv,
                                                 const float* __restrict__ b2,
                                                 float* __restrict__ out, int N) {
    const int wid  = (blockIdx.x * 256 + threadIdx.x) >> 6;
    const int lane = threadIdx.x & 63;
    if (wid >= N) return;
    const int start = (int)off[wid];
    const int end   = (int)off[wid + 1];
    const bool act = lane < D_OUT;
    float acc = act ? h2s[(size_t)wid * D_OUT + lane] : 0.0f;
    for (int base = start; base < end; base += 64) {
        const int nb = min(64, end - base);
        int sv = (base + lane < end) ? csr_src[base + lane] : 0;
        int j = 0;
        for (; j + 3 < nb; j += 4) {
            int s0 = __shfl(sv, j),     s1 = __shfl(sv, j + 1);
            int s2 = __shfl(sv, j + 2), s3 = __shfl(sv, j + 3);
            if (act) {
                float v0 = h2s[(size_t)s0 * D_OUT + lane];
                float v1 = h2s[(size_t)s1 * D_OUT + lane];
                float v2 = h2s[(size_t)s2 * D_OUT + lane];
                float v3 = h2s[(size_t)s3 * D_OUT + lane];
                acc += (v0 + v1) + (v2 + v3);
            }
        }
        for (; j < nb; ++j) {
            int s = __shfl(sv, j);
            if (act) acc += h2s[(size_t)s * D_OUT + lane];
        }
    }
    if (act) out[(size_t)wid * D_OUT + lane] = dinv[wid] * acc + b2[lane];
}

extern "C" void kernel_launch(void* const* d_in, const int* in_sizes, int n_in,
                              void* d_out, int out_size, void* d_ws, size_t ws_size,
                              hipStream_t stream) {
    const float* x  = (const float*)d_in[0];
    const int*  eix = (const int*)d_in[1];   // [2, E] int32 per harness contract
    const float* W1 = (const float*)d_in[2];
    const float* b1 = (const float*)d_in[3];
    const float* W2 = (const float*)d_in[4];
    const float* b2 = (const float*)d_in[5];
    float* out = (float*)d_out;

    const int N = in_sizes[0] / D_IN;
    const int E = in_sizes[1] / 2;
    const int* src = eix;
    const int* dst = eix + E;
    const int NB = (N + 255) / 256;   // scan blocks (<=512 required by k_scan2)

    // workspace layout: deg | dinv | offsets(N+1) | bsums(512) | csr_src(E) | h1s | hidden
    // rank aliases hidden (rank dead before gather1 writes hidden).
    // h2s aliases h1s (h1s dead after gather1).
    char* ws = (char*)d_ws;
    size_t off_b = 0;
    auto alloc = [&](size_t bytes) {
        void* p = ws + off_b;
        off_b = (off_b + bytes + 255) & ~(size_t)255;
        return p;
    };
    unsigned int* deg     = (unsigned int*)alloc((size_t)N * 4);
    float*        dinv    = (float*)alloc((size_t)N * 4);
    unsigned int* offsets = (unsigned int*)alloc((size_t)(N + 1) * 4);
    unsigned int* bsums   = (unsigned int*)alloc(512 * 4);
    int*          csr_src = (int*)alloc((size_t)E * 4);
    float*        h1s     = (float*)alloc((size_t)N * D_HID * 4);
    float*        hidden  = (float*)alloc((size_t)N * D_HID * 4);
    float*        h2s     = h1s;                    // alias: h1s dead after gather1
    unsigned int* rank    = (unsigned int*)hidden;  // alias: rank dead before gather1 writes hidden

    hipMemsetAsync(deg, 0, (size_t)N * 4, stream);

    // CSR build (atomic-free fill via rank trick)
    k_deg  <<<(E + 255) / 256, 256, 0, stream>>>(dst, deg, rank, E);
    k_dinv <<<NB, 256, 0, stream>>>(deg, dinv, N);
    k_scan1<<<NB, 256, 0, stream>>>(deg, offsets, bsums, N);
    k_scan2<<<1, 512, 0, stream>>>(bsums, NB);
    k_scan3<<<NB, 256, 0, stream>>>(offsets, bsums, N, E);
    k_fill <<<(E + 255) / 256, 256, 0, stream>>>(src, dst, offsets, rank, csr_src, E);

    // layer 1
    k_gemm1  <<<(N + 3) / 4, 256, 0, stream>>>(x, W1, dinv, h1s, N);
    k_gather1<<<(N + 3) / 4, 256, 0, stream>>>(offsets, csr_src, h1s, dinv, b1, hidden, N);

    // layer 2
    k_gemm2  <<<(N + 7) / 8, 320, 0, stream>>>(hidden, W2, dinv, h2s, N);
    k_gather2<<<(N + 3) / 4, 256, 0, stream>>>(offsets, csr_src, h2s, dinv, b2, out, N);
}

// Round 10
// 383.410 us; speedup vs baseline: 2.1063x; 1.1809x over previous
//
#include <hip/hip_runtime.h>

#define D_IN  128
#define D_HID 64
#define D_OUT 40

// ---- degree count + edge rank (self-loop +1 folded into k_dinv) ----
__global__ __launch_bounds__(256) void k_deg(const int* __restrict__ dst,
                                             unsigned int* __restrict__ cnt,
                                             unsigned int* __restrict__ rank, int E) {
    int e = blockIdx.x * 256 + threadIdx.x;
    if (e < E) rank[e] = atomicAdd(&cnt[dst[e]], 1u);
}

__global__ __launch_bounds__(256) void k_dinv(const unsigned int* __restrict__ deg,
                                              float* __restrict__ dinv, int N) {
    int i = blockIdx.x * 256 + threadIdx.x;
    if (i < N) dinv[i] = rsqrtf((float)(deg[i] + 1u));
}

// ---- exclusive scan of deg -> offsets (3-kernel hierarchical) ----
__global__ __launch_bounds__(256) void k_scan1(const unsigned int* __restrict__ deg,
                                               unsigned int* __restrict__ off,
                                               unsigned int* __restrict__ bsum, int N) {
    __shared__ unsigned int s[256];
    const int tid = threadIdx.x;
    const int i = blockIdx.x * 256 + tid;
    unsigned int v = (i < N) ? deg[i] : 0u;
    s[tid] = v;
    __syncthreads();
    for (int d = 1; d < 256; d <<= 1) {
        unsigned int t = (tid >= d) ? s[tid - d] : 0u;
        __syncthreads();
        s[tid] += t;
        __syncthreads();
    }
    if (i < N) off[i] = s[tid] - v;              // exclusive
    if (tid == 255) bsum[blockIdx.x] = s[tid];   // block total
}

__global__ __launch_bounds__(512) void k_scan2(unsigned int* __restrict__ bsum, int NB) {
    __shared__ unsigned int s[512];
    const int tid = threadIdx.x;
    unsigned int v = (tid < NB) ? bsum[tid] : 0u;
    s[tid] = v;
    __syncthreads();
    for (int d = 1; d < 512; d <<= 1) {
        unsigned int t = (tid >= d) ? s[tid - d] : 0u;
        __syncthreads();
        s[tid] += t;
        __syncthreads();
    }
    if (tid < NB) bsum[tid] = s[tid] - v;        // exclusive over block sums
}

__global__ __launch_bounds__(256) void k_scan3(unsigned int* __restrict__ off,
                                               const unsigned int* __restrict__ bsum,
                                               int N, int E) {
    int i = blockIdx.x * 256 + threadIdx.x;
    if (i < N) off[i] += bsum[blockIdx.x];
    if (i == 0) off[N] = (unsigned int)E;
}

// ---- atomic-free counting-sort fill: csr_src[off[dst]+rank] = src ----
__global__ __launch_bounds__(256) void k_fill(const int* __restrict__ src,
                                              const int* __restrict__ dst,
                                              const unsigned int* __restrict__ off,
                                              const unsigned int* __restrict__ rank,
                                              int* __restrict__ csr_src, int E) {
    int e = blockIdx.x * 256 + threadIdx.x;
    if (e >= E) return;
    csr_src[off[dst[e]] + rank[e]] = src[e];
}

// ---- h1s = (x @ W1) * dinv[row] ; 16 rows/block, thread = 1 row x 4 cols ----
// LDS bytes/FMA ~1.1 (broadcast-shared reads) vs 8 in the naive mapping.
__global__ __launch_bounds__(256) void k_gemm1(const float* __restrict__ x,
                                               const float* __restrict__ W1,
                                               const float* __restrict__ dinv,
                                               float* __restrict__ h1s, int N) {
    __shared__ float w[D_IN * D_HID];        // 32 KB, w[k*64+c]
    __shared__ float xs[16][D_IN + 4];       // pad 4: bank-spread, 16B-aligned rows
    const int tid = threadIdx.x;
    // stage W1 (float4)
    const float4* W4 = (const float4*)W1;
    float4* w4 = (float4*)w;
    for (int i = tid; i < D_IN * D_HID / 4; i += 256) w4[i] = W4[i];
    // stage 16 x-rows (float4); N % 16 == 0 so block is always full
    const int row0 = blockIdx.x * 16;
    const float4* X4 = (const float4*)(x + (size_t)row0 * D_IN);
    for (int i = tid; i < 16 * D_IN / 4; i += 256) {
        float4 v = X4[i];
        int r = i >> 5;              // (i*4)/128
        int k = (i & 31) * 4;
        *(float4*)&xs[r][k] = v;
    }
    __syncthreads();
    const int r  = tid >> 4;                 // 0..15
    const int c4 = (tid & 15) * 4;           // 0,4,..,60
    float a0 = 0, a1 = 0, a2 = 0, a3 = 0;
#pragma unroll 8
    for (int k = 0; k < D_IN; ++k) {
        float  xv = xs[r][k];                        // 16-lane broadcast
        float4 wv = *(const float4*)&w[k * D_HID + c4]; // 4-lane broadcast
        a0 = fmaf(xv, wv.x, a0);
        a1 = fmaf(xv, wv.y, a1);
        a2 = fmaf(xv, wv.z, a2);
        a3 = fmaf(xv, wv.w, a3);
    }
    const int row = row0 + r;
    if (row < N) {
        float dv = dinv[row];
        float4 o = {a0 * dv, a1 * dv, a2 * dv, a3 * dv};
        *(float4*)&h1s[(size_t)row * D_HID + c4] = o;
    }
}

// ---- h2s = (hidden @ W2) * dinv[row] ; 16 rows/block, thread = 1 row x 2 cols ----
__global__ __launch_bounds__(320) void k_gemm2(const float* __restrict__ hid,
                                               const float* __restrict__ W2,
                                               const float* __restrict__ dinv,
                                               float* __restrict__ h2s, int N) {
    __shared__ float w[D_HID * D_OUT];       // 10 KB, w[k*40+c]
    __shared__ float xs[16][D_HID + 4];      // pad 4: bank-spread, 16B-aligned rows
    const int tid = threadIdx.x;
    // stage W2 (float2)
    const float2* W22 = (const float2*)W2;
    float2* w2 = (float2*)w;
    for (int i = tid; i < D_HID * D_OUT / 2; i += 320) w2[i] = W22[i];
    // stage 16 hidden-rows (float4): 256 float4s
    const int row0 = blockIdx.x * 16;
    const float4* X4 = (const float4*)(hid + (size_t)row0 * D_HID);
    for (int i = tid; i < 16 * D_HID / 4; i += 320) {
        float4 v = X4[i];
        int r = i >> 4;              // (i*4)/64
        int k = (i & 15) * 4;
        *(float4*)&xs[r][k] = v;
    }
    __syncthreads();
    const int r  = tid / 20;                 // 0..15
    const int c2 = (tid % 20) * 2;           // 0,2,..,38
    float a0 = 0, a1 = 0;
#pragma unroll 8
    for (int k = 0; k < D_HID; ++k) {
        float  xv = xs[r][k];
        float2 wv = *(const float2*)&w[k * D_OUT + c2];
        a0 = fmaf(xv, wv.x, a0);
        a1 = fmaf(xv, wv.y, a1);
    }
    const int row = row0 + r;
    if (row < N) {
        float dv = dinv[row];
        float2 o = {a0 * dv, a1 * dv};
        *(float2*)&h2s[(size_t)row * D_OUT + c2] = o;
    }
}

// ---- gather1: hidden[n] = relu(dinv[n]*(Σ_in h1s[src] + h1s[n]) + b1) ----
__global__ __launch_bounds__(256) void k_gather1(const unsigned int* __restrict__ off,
                                                 const int* __restrict__ csr_src,
                                                 const float* __restrict__ h1s,
                                                 const float* __restrict__ dinv,
                                                 const float* __restrict__ b1,
                                                 float* __restrict__ hidden, int N) {
    const int wid  = (blockIdx.x * 256 + threadIdx.x) >> 6;
    const int lane = threadIdx.x & 63;
    if (wid >= N) return;
    const int start = (int)off[wid];
    const int end   = (int)off[wid + 1];
    float acc = h1s[(size_t)wid * D_HID + lane];   // self-loop term
    for (int base = start; base < end; base += 64) {
        const int nb = min(64, end - base);
        int sv = (base + lane < end) ? csr_src[base + lane] : 0;
        int j = 0;
        for (; j + 3 < nb; j += 4) {
            int s0 = __shfl(sv, j),     s1 = __shfl(sv, j + 1);
            int s2 = __shfl(sv, j + 2), s3 = __shfl(sv, j + 3);
            float v0 = h1s[(size_t)s0 * D_HID + lane];
            float v1 = h1s[(size_t)s1 * D_HID + lane];
            float v2 = h1s[(size_t)s2 * D_HID + lane];
            float v3 = h1s[(size_t)s3 * D_HID + lane];
            acc += (v0 + v1) + (v2 + v3);
        }
        for (; j < nb; ++j) {
            int s = __shfl(sv, j);
            acc += h1s[(size_t)s * D_HID + lane];
        }
    }
    float v = dinv[wid] * acc + b1[lane];
    hidden[(size_t)wid * D_HID + lane] = v > 0.0f ? v : 0.0f;
}

// ---- gather2: out[n] = dinv[n]*(Σ_in h2s[src] + h2s[n]) + b2 ----
__global__ __launch_bounds__(256) void k_gather2(const unsigned int* __restrict__ off,
                                                 const int* __restrict__ csr_src,
                                                 const float* __restrict__ h2s,
                                                 const float* __restrict__ dinv,
                                                 const float* __restrict__ b2,
                                                 float* __restrict__ out, int N) {
    const int wid  = (blockIdx.x * 256 + threadIdx.x) >> 6;
    const int lane = threadIdx.x & 63;
    if (wid >= N) return;
    const int start = (int)off[wid];
    const int end   = (int)off[wid + 1];
    const bool act = lane < D_OUT;
    float acc = act ? h2s[(size_t)wid * D_OUT + lane] : 0.0f;
    for (int base = start; base < end; base += 64) {
        const int nb = min(64, end - base);
        int sv = (base + lane < end) ? csr_src[base + lane] : 0;
        int j = 0;
        for (; j + 3 < nb; j += 4) {
            int s0 = __shfl(sv, j),     s1 = __shfl(sv, j + 1);
            int s2 = __shfl(sv, j + 2), s3 = __shfl(sv, j + 3);
            if (act) {
                float v0 = h2s[(size_t)s0 * D_OUT + lane];
                float v1 = h2s[(size_t)s1 * D_OUT + lane];
                float v2 = h2s[(size_t)s2 * D_OUT + lane];
                float v3 = h2s[(size_t)s3 * D_OUT + lane];
                acc += (v0 + v1) + (v2 + v3);
            }
        }
        for (; j < nb; ++j) {
            int s = __shfl(sv, j);
            if (act) acc += h2s[(size_t)s * D_OUT + lane];
        }
    }
    if (act) out[(size_t)wid * D_OUT + lane] = dinv[wid] * acc + b2[lane];
}

extern "C" void kernel_launch(void* const* d_in, const int* in_sizes, int n_in,
                              void* d_out, int out_size, void* d_ws, size_t ws_size,
                              hipStream_t stream) {
    const float* x  = (const float*)d_in[0];
    const int*  eix = (const int*)d_in[1];   // [2, E] int32 per harness contract
    const float* W1 = (const float*)d_in[2];
    const float* b1 = (const float*)d_in[3];
    const float* W2 = (const float*)d_in[4];
    const float* b2 = (const float*)d_in[5];
    float* out = (float*)d_out;

    const int N = in_sizes[0] / D_IN;
    const int E = in_sizes[1] / 2;
    const int* src = eix;
    const int* dst = eix + E;
    const int NB = (N + 255) / 256;   // scan blocks (<=512 required by k_scan2)

    // workspace layout: deg | dinv | offsets(N+1) | bsums(512) | csr_src(E) | h1s | hidden
    // rank aliases hidden (rank dead before gather1 writes hidden).
    // h2s aliases h1s (h1s dead after gather1).
    char* ws = (char*)d_ws;
    size_t off_b = 0;
    auto alloc = [&](size_t bytes) {
        void* p = ws + off_b;
        off_b = (off_b + bytes + 255) & ~(size_t)255;
        return p;
    };
    unsigned int* deg     = (unsigned int*)alloc((size_t)N * 4);
    float*        dinv    = (float*)alloc((size_t)N * 4);
    unsigned int* offsets = (unsigned int*)alloc((size_t)(N + 1) * 4);
    unsigned int* bsums   = (unsigned int*)alloc(512 * 4);
    int*          csr_src = (int*)alloc((size_t)E * 4);
    float*        h1s     = (float*)alloc((size_t)N * D_HID * 4);
    float*        hidden  = (float*)alloc((size_t)N * D_HID * 4);
    float*        h2s     = h1s;                    // alias: h1s dead after gather1
    unsigned int* rank    = (unsigned int*)hidden;  // alias: rank dead before gather1 writes hidden

    hipMemsetAsync(deg, 0, (size_t)N * 4, stream);

    // CSR build (atomic-free fill via rank trick)
    k_deg  <<<(E + 255) / 256, 256, 0, stream>>>(dst, deg, rank, E);
    k_dinv <<<NB, 256, 0, stream>>>(deg, dinv, N);
    k_scan1<<<NB, 256, 0, stream>>>(deg, offsets, bsums, N);
    k_scan2<<<1, 512, 0, stream>>>(bsums, NB);
    k_scan3<<<NB, 256, 0, stream>>>(offsets, bsums, N, E);
    k_fill <<<(E + 255) / 256, 256, 0, stream>>>(src, dst, offsets, rank, csr_src, E);

    // layer 1
    k_gemm1  <<<(N + 15) / 16, 256, 0, stream>>>(x, W1, dinv, h1s, N);
    k_gather1<<<(N + 3) / 4, 256, 0, stream>>>(offsets, csr_src, h1s, dinv, b1, hidden, N);

    // layer 2
    k_gemm2  <<<(N + 15) / 16, 320, 0, stream>>>(hidden, W2, dinv, h2s, N);
    k_gather2<<<(N + 3) / 4, 256, 0, stream>>>(offsets, csr_src, h2s, dinv, b2, out, N);
}

// Round 11
// 340.165 us; speedup vs baseline: 2.3741x; 1.1271x over previous
//
#include <hip/hip_runtime.h>

#define D_IN  128
#define D_HID 64
#define D_OUT 40

static __device__ __forceinline__ unsigned short f2bf(float f) {
    unsigned int u = __float_as_uint(f);
    unsigned int r = (u + 0x7fffu + ((u >> 16) & 1u)) >> 16;   // RNE
    return (unsigned short)r;
}
static __device__ __forceinline__ float bflo(unsigned int u) {
    return __uint_as_float(u << 16);
}
static __device__ __forceinline__ float bfhi(unsigned int u) {
    return __uint_as_float(u & 0xffff0000u);
}

// ---- degree count + edge rank (self-loop +1 folded into dinv) ----
// At the random-line atomic-fabric roofline (~24 G lines/s) — structural.
__global__ __launch_bounds__(256) void k_deg(const int* __restrict__ dst,
                                             unsigned int* __restrict__ cnt,
                                             unsigned int* __restrict__ rank, int E) {
    int e = blockIdx.x * 256 + threadIdx.x;
    if (e < E) rank[e] = atomicAdd(&cnt[dst[e]], 1u);
}

// ---- scan1 + fused dinv = rsqrt(deg+1) ----
__global__ __launch_bounds__(256) void k_scan1(const unsigned int* __restrict__ deg,
                                               unsigned int* __restrict__ off,
                                               unsigned int* __restrict__ bsum,
                                               float* __restrict__ dinv, int N) {
    __shared__ unsigned int s[256];
    const int tid = threadIdx.x;
    const int i = blockIdx.x * 256 + tid;
    unsigned int v = (i < N) ? deg[i] : 0u;
    if (i < N) dinv[i] = rsqrtf((float)(v + 1u));
    s[tid] = v;
    __syncthreads();
    for (int d = 1; d < 256; d <<= 1) {
        unsigned int t = (tid >= d) ? s[tid - d] : 0u;
        __syncthreads();
        s[tid] += t;
        __syncthreads();
    }
    if (i < N) off[i] = s[tid] - v;              // exclusive
    if (tid == 255) bsum[blockIdx.x] = s[tid];   // block total
}

__global__ __launch_bounds__(512) void k_scan2(unsigned int* __restrict__ bsum, int NB) {
    __shared__ unsigned int s[512];
    const int tid = threadIdx.x;
    unsigned int v = (tid < NB) ? bsum[tid] : 0u;
    s[tid] = v;
    __syncthreads();
    for (int d = 1; d < 512; d <<= 1) {
        unsigned int t = (tid >= d) ? s[tid - d] : 0u;
        __syncthreads();
        s[tid] += t;
        __syncthreads();
    }
    if (tid < NB) bsum[tid] = s[tid] - v;        // exclusive over block sums
}

__global__ __launch_bounds__(256) void k_scan3(unsigned int* __restrict__ off,
                                               const unsigned int* __restrict__ bsum,
                                               int N, int E) {
    int i = blockIdx.x * 256 + threadIdx.x;
    if (i < N) off[i] += bsum[blockIdx.x];
    if (i == 0) off[N] = (unsigned int)E;
}

// ---- atomic-free counting-sort fill: csr_src[off[dst]+rank] = src ----
__global__ __launch_bounds__(256) void k_fill(const int* __restrict__ src,
                                              const int* __restrict__ dst,
                                              const unsigned int* __restrict__ off,
                                              const unsigned int* __restrict__ rank,
                                              int* __restrict__ csr_src, int E) {
    int e = blockIdx.x * 256 + threadIdx.x;
    if (e >= E) return;
    csr_src[off[dst[e]] + rank[e]] = src[e];
}

// ---- h1s(bf16) = (x @ W1) * dinv[row] ; 16 rows/block, thread = 1 row x 4 cols ----
__global__ __launch_bounds__(256) void k_gemm1(const float* __restrict__ x,
                                               const float* __restrict__ W1,
                                               const float* __restrict__ dinv,
                                               unsigned short* __restrict__ h1s, int N) {
    __shared__ float w[D_IN * D_HID];        // 32 KB, w[k*64+c]
    __shared__ float xs[16][D_IN + 4];
    const int tid = threadIdx.x;
    const float4* W4 = (const float4*)W1;
    float4* w4 = (float4*)w;
    for (int i = tid; i < D_IN * D_HID / 4; i += 256) w4[i] = W4[i];
    const int row0 = blockIdx.x * 16;
    const float4* X4 = (const float4*)(x + (size_t)row0 * D_IN);
    for (int i = tid; i < 16 * D_IN / 4; i += 256) {
        float4 v = X4[i];
        int r = i >> 5;
        int k = (i & 31) * 4;
        *(float4*)&xs[r][k] = v;
    }
    __syncthreads();
    const int r  = tid >> 4;
    const int c4 = (tid & 15) * 4;
    float a0 = 0, a1 = 0, a2 = 0, a3 = 0;
#pragma unroll 8
    for (int k = 0; k < D_IN; ++k) {
        float  xv = xs[r][k];
        float4 wv = *(const float4*)&w[k * D_HID + c4];
        a0 = fmaf(xv, wv.x, a0);
        a1 = fmaf(xv, wv.y, a1);
        a2 = fmaf(xv, wv.z, a2);
        a3 = fmaf(xv, wv.w, a3);
    }
    const int row = row0 + r;
    if (row < N) {
        float dv = dinv[row];
        uint2 o;
        o.x = (unsigned)f2bf(a0 * dv) | ((unsigned)f2bf(a1 * dv) << 16);
        o.y = (unsigned)f2bf(a2 * dv) | ((unsigned)f2bf(a3 * dv) << 16);
        *(uint2*)&h1s[(size_t)row * D_HID + c4] = o;
    }
}

// ---- h2s(bf16) = (hidden @ W2) * dinv[row] ; 16 rows/block, thread = 1 row x 2 cols ----
__global__ __launch_bounds__(320) void k_gemm2(const float* __restrict__ hid,
                                               const float* __restrict__ W2,
                                               const float* __restrict__ dinv,
                                               unsigned short* __restrict__ h2s, int N) {
    __shared__ float w[D_HID * D_OUT];       // 10 KB
    __shared__ float xs[16][D_HID + 4];
    const int tid = threadIdx.x;
    const float2* W22 = (const float2*)W2;
    float2* w2 = (float2*)w;
    for (int i = tid; i < D_HID * D_OUT / 2; i += 320) w2[i] = W22[i];
    const int row0 = blockIdx.x * 16;
    const float4* X4 = (const float4*)(hid + (size_t)row0 * D_HID);
    for (int i = tid; i < 16 * D_HID / 4; i += 320) {
        float4 v = X4[i];
        int r = i >> 4;
        int k = (i & 15) * 4;
        *(float4*)&xs[r][k] = v;
    }
    __syncthreads();
    const int r  = tid / 20;
    const int c2 = (tid % 20) * 2;
    float a0 = 0, a1 = 0;
#pragma unroll 8
    for (int k = 0; k < D_HID; ++k) {
        float  xv = xs[r][k];
        float2 wv = *(const float2*)&w[k * D_OUT + c2];
        a0 = fmaf(xv, wv.x, a0);
        a1 = fmaf(xv, wv.y, a1);
    }
    const int row = row0 + r;
    if (row < N) {
        float dv = dinv[row];
        unsigned int o = (unsigned)f2bf(a0 * dv) | ((unsigned)f2bf(a1 * dv) << 16);
        *(unsigned int*)&h2s[(size_t)row * D_OUT + c2] = o;
    }
}

// ---- gather1: 2 nodes per wave (32 lanes each), lane = 2 packed bf16 cols ----
// hidden[n] = relu(dinv[n]*(Σ_in h1s[src] + h1s[n]) + b1)  [fp32 out]
__global__ __launch_bounds__(256) void k_gather1(const unsigned int* __restrict__ off,
                                                 const int* __restrict__ csr_src,
                                                 const unsigned int* __restrict__ h1s, // bf16x2
                                                 const float* __restrict__ dinv,
                                                 const float* __restrict__ b1,
                                                 float* __restrict__ hidden, int N) {
    const int gtid = blockIdx.x * 256 + threadIdx.x;
    const int wid2 = gtid >> 6;              // wave id
    const int lane = threadIdx.x & 63;
    const int half = lane >> 5;              // 0/1 -> node within pair
    const int hl   = lane & 31;              // col-pair index 0..31
    const int node = wid2 * 2 + half;
    if (node >= N) return;
    const int start = (int)off[node];
    const int end   = (int)off[node + 1];
    // self term
    unsigned int u = h1s[(size_t)node * 32 + hl];
    float a0 = bflo(u), a1 = bfhi(u);
    for (int base = start; base < end; base += 32) {
        const int nb = min(32, end - base);
        int sv = (base + hl < end) ? csr_src[base + hl] : 0;
        int j = 0;
        for (; j + 3 < nb; j += 4) {
            int s0 = __shfl(sv, j, 32),     s1 = __shfl(sv, j + 1, 32);
            int s2 = __shfl(sv, j + 2, 32), s3 = __shfl(sv, j + 3, 32);
            unsigned int u0 = h1s[(size_t)s0 * 32 + hl];
            unsigned int u1 = h1s[(size_t)s1 * 32 + hl];
            unsigned int u2 = h1s[(size_t)s2 * 32 + hl];
            unsigned int u3 = h1s[(size_t)s3 * 32 + hl];
            a0 += (bflo(u0) + bflo(u1)) + (bflo(u2) + bflo(u3));
            a1 += (bfhi(u0) + bfhi(u1)) + (bfhi(u2) + bfhi(u3));
        }
        for (; j < nb; ++j) {
            int s = __shfl(sv, j, 32);
            unsigned int uu = h1s[(size_t)s * 32 + hl];
            a0 += bflo(uu);
            a1 += bfhi(uu);
        }
    }
    const float dv = dinv[node];
    const float2 bb = *(const float2*)&b1[hl * 2];
    float v0 = dv * a0 + bb.x;
    float v1 = dv * a1 + bb.y;
    float2 o = {v0 > 0.0f ? v0 : 0.0f, v1 > 0.0f ? v1 : 0.0f};
    *(float2*)&hidden[(size_t)node * D_HID + hl * 2] = o;
}

// ---- gather2: 2 nodes per wave; lanes hl<20 handle 2 cols each ----
// out[n] = dinv[n]*(Σ_in h2s[src] + h2s[n]) + b2   [fp32 out]
__global__ __launch_bounds__(256) void k_gather2(const unsigned int* __restrict__ off,
                                                 const int* __restrict__ csr_src,
                                                 const unsigned int* __restrict__ h2s, // bf16x2
                                                 const float* __restrict__ dinv,
                                                 const float* __restrict__ b2,
                                                 float* __restrict__ out, int N) {
    const int gtid = blockIdx.x * 256 + threadIdx.x;
    const int wid2 = gtid >> 6;
    const int lane = threadIdx.x & 63;
    const int half = lane >> 5;
    const int hl   = lane & 31;
    const int node = wid2 * 2 + half;
    if (node >= N) return;
    const int start = (int)off[node];
    const int end   = (int)off[node + 1];
    const bool act = hl < 20;
    float a0 = 0.0f, a1 = 0.0f;
    if (act) {
        unsigned int u = h2s[(size_t)node * 20 + hl];
        a0 = bflo(u); a1 = bfhi(u);
    }
    for (int base = start; base < end; base += 32) {
        const int nb = min(32, end - base);
        int sv = (base + hl < end) ? csr_src[base + hl] : 0;
        int j = 0;
        for (; j + 3 < nb; j += 4) {
            int s0 = __shfl(sv, j, 32),     s1 = __shfl(sv, j + 1, 32);
            int s2 = __shfl(sv, j + 2, 32), s3 = __shfl(sv, j + 3, 32);
            if (act) {
                unsigned int u0 = h2s[(size_t)s0 * 20 + hl];
                unsigned int u1 = h2s[(size_t)s1 * 20 + hl];
                unsigned int u2 = h2s[(size_t)s2 * 20 + hl];
                unsigned int u3 = h2s[(size_t)s3 * 20 + hl];
                a0 += (bflo(u0) + bflo(u1)) + (bflo(u2) + bflo(u3));
                a1 += (bfhi(u0) + bfhi(u1)) + (bfhi(u2) + bfhi(u3));
            }
        }
        for (; j < nb; ++j) {
            int s = __shfl(sv, j, 32);
            if (act) {
                unsigned int uu = h2s[(size_t)s * 20 + hl];
                a0 += bflo(uu);
                a1 += bfhi(uu);
            }
        }
    }
    if (act) {
        const float dv = dinv[node];
        const float2 bb = *(const float2*)&b2[hl * 2];
        float2 o = {dv * a0 + bb.x, dv * a1 + bb.y};
        *(float2*)&out[(size_t)node * D_OUT + hl * 2] = o;
    }
}

extern "C" void kernel_launch(void* const* d_in, const int* in_sizes, int n_in,
                              void* d_out, int out_size, void* d_ws, size_t ws_size,
                              hipStream_t stream) {
    const float* x  = (const float*)d_in[0];
    const int*  eix = (const int*)d_in[1];   // [2, E] int32 per harness contract
    const float* W1 = (const float*)d_in[2];
    const float* b1 = (const float*)d_in[3];
    const float* W2 = (const float*)d_in[4];
    const float* b2 = (const float*)d_in[5];
    float* out = (float*)d_out;

    const int N = in_sizes[0] / D_IN;
    const int E = in_sizes[1] / 2;
    const int* src = eix;
    const int* dst = eix + E;
    const int NB = (N + 255) / 256;   // scan blocks (<=512 required by k_scan2)

    // ws layout: deg | dinv | offsets(N+1) | bsums(512) | csr_src(E) | h1s(bf16) | hidden(f32)
    // h2s aliases h1s (dead after gather1); rank aliases hidden (dead before gather1 writes).
    char* ws = (char*)d_ws;
    size_t off_b = 0;
    auto alloc = [&](size_t bytes) {
        void* p = ws + off_b;
        off_b = (off_b + bytes + 255) & ~(size_t)255;
        return p;
    };
    unsigned int*   deg     = (unsigned int*)alloc((size_t)N * 4);
    float*          dinv    = (float*)alloc((size_t)N * 4);
    unsigned int*   offsets = (unsigned int*)alloc((size_t)(N + 1) * 4);
    unsigned int*   bsums   = (unsigned int*)alloc(512 * 4);
    int*            csr_src = (int*)alloc((size_t)E * 4);
    unsigned short* h1s     = (unsigned short*)alloc((size_t)N * D_HID * 2);
    float*          hidden  = (float*)alloc((size_t)N * D_HID * 4);
    unsigned short* h2s     = h1s;                    // alias: h1s dead after gather1
    unsigned int*   rank    = (unsigned int*)hidden;  // alias: rank dead before gather1

    hipMemsetAsync(deg, 0, (size_t)N * 4, stream);

    // CSR build
    k_deg  <<<(E + 255) / 256, 256, 0, stream>>>(dst, deg, rank, E);
    k_scan1<<<NB, 256, 0, stream>>>(deg, offsets, bsums, dinv, N);
    k_scan2<<<1, 512, 0, stream>>>(bsums, NB);
    k_scan3<<<NB, 256, 0, stream>>>(offsets, bsums, N, E);
    k_fill <<<(E + 255) / 256, 256, 0, stream>>>(src, dst, offsets, rank, csr_src, E);

    const int gwaves = (N + 1) / 2;                  // 2 nodes per wave
    const int gblocks = (gwaves + 3) / 4;            // 4 waves per block

    // layer 1
    k_gemm1  <<<(N + 15) / 16, 256, 0, stream>>>(x, W1, dinv, h1s, N);
    k_gather1<<<gblocks, 256, 0, stream>>>(offsets, csr_src, (const unsigned int*)h1s, dinv, b1, hidden, N);

    // layer 2
    k_gemm2  <<<(N + 15) / 16, 320, 0, stream>>>(hidden, W2, dinv, h2s, N);
    k_gather2<<<gblocks, 256, 0, stream>>>(offsets, csr_src, (const unsigned int*)h2s, dinv, b2, out, N);
}

// Round 12
// 328.194 us; speedup vs baseline: 2.4607x; 1.0365x over previous
//
#include <hip/hip_runtime.h>

#define D_IN  128
#define D_HID 64
#define D_OUT 40

static __device__ __forceinline__ unsigned short f2bf(float f) {
    unsigned int u = __float_as_uint(f);
    unsigned int r = (u + 0x7fffu + ((u >> 16) & 1u)) >> 16;   // RNE
    return (unsigned short)r;
}
static __device__ __forceinline__ float bflo(unsigned int u) {
    return __uint_as_float(u << 16);
}
static __device__ __forceinline__ float bfhi(unsigned int u) {
    return __uint_as_float(u & 0xffff0000u);
}

// ---- FUSED: degree/rank atomics (blocks < DB) + gemm1 (remaining blocks) ----
// deg role is fabric-latency-bound with idle VALU; gemm1 hides under it.
// h1s is UNSCALED bf16 (dinv not computed yet); gather applies dinv[src].
__global__ __launch_bounds__(256) void k_deg_g1(const int* __restrict__ dst,
                                                unsigned int* __restrict__ cnt,
                                                unsigned int* __restrict__ rank, int E, int DB,
                                                const float* __restrict__ x,
                                                const float* __restrict__ W1,
                                                unsigned short* __restrict__ h1s, int N) {
    __shared__ float w[D_IN * D_HID];        // 32 KB
    __shared__ float xs[16][D_IN + 4];
    if ((int)blockIdx.x < DB) {              // ---- deg role ----
        int e = blockIdx.x * 256 + threadIdx.x;
        if (e < E) rank[e] = atomicAdd(&cnt[dst[e]], 1u);
        return;
    }
    // ---- gemm1 role ----
    const int tid = threadIdx.x;
    const float4* W4 = (const float4*)W1;
    float4* w4 = (float4*)w;
    for (int i = tid; i < D_IN * D_HID / 4; i += 256) w4[i] = W4[i];
    const int row0 = (blockIdx.x - DB) * 16;
    const float4* X4 = (const float4*)(x + (size_t)row0 * D_IN);
    for (int i = tid; i < 16 * D_IN / 4; i += 256) {
        float4 v = X4[i];
        int r = i >> 5;
        int k = (i & 31) * 4;
        *(float4*)&xs[r][k] = v;
    }
    __syncthreads();
    const int r  = tid >> 4;
    const int c4 = (tid & 15) * 4;
    float a0 = 0, a1 = 0, a2 = 0, a3 = 0;
#pragma unroll 8
    for (int k = 0; k < D_IN; ++k) {
        float  xv = xs[r][k];
        float4 wv = *(const float4*)&w[k * D_HID + c4];
        a0 = fmaf(xv, wv.x, a0);
        a1 = fmaf(xv, wv.y, a1);
        a2 = fmaf(xv, wv.z, a2);
        a3 = fmaf(xv, wv.w, a3);
    }
    const int row = row0 + r;
    if (row < N) {
        uint2 o;
        o.x = (unsigned)f2bf(a0) | ((unsigned)f2bf(a1) << 16);
        o.y = (unsigned)f2bf(a2) | ((unsigned)f2bf(a3) << 16);
        *(uint2*)&h1s[(size_t)row * D_HID + c4] = o;
    }
}

// ---- scan1 + fused dinv = rsqrt(deg+1) ----
__global__ __launch_bounds__(256) void k_scan1(const unsigned int* __restrict__ deg,
                                               unsigned int* __restrict__ off,
                                               unsigned int* __restrict__ bsum,
                                               float* __restrict__ dinv, int N) {
    __shared__ unsigned int s[256];
    const int tid = threadIdx.x;
    const int i = blockIdx.x * 256 + tid;
    unsigned int v = (i < N) ? deg[i] : 0u;
    if (i < N) dinv[i] = rsqrtf((float)(v + 1u));
    s[tid] = v;
    __syncthreads();
    for (int d = 1; d < 256; d <<= 1) {
        unsigned int t = (tid >= d) ? s[tid - d] : 0u;
        __syncthreads();
        s[tid] += t;
        __syncthreads();
    }
    if (i < N) off[i] = s[tid] - v;              // exclusive
    if (tid == 255) bsum[blockIdx.x] = s[tid];   // block total
}

__global__ __launch_bounds__(512) void k_scan2(unsigned int* __restrict__ bsum, int NB) {
    __shared__ unsigned int s[512];
    const int tid = threadIdx.x;
    unsigned int v = (tid < NB) ? bsum[tid] : 0u;
    s[tid] = v;
    __syncthreads();
    for (int d = 1; d < 512; d <<= 1) {
        unsigned int t = (tid >= d) ? s[tid - d] : 0u;
        __syncthreads();
        s[tid] += t;
        __syncthreads();
    }
    if (tid < NB) bsum[tid] = s[tid] - v;        // exclusive over block sums
}

__global__ __launch_bounds__(256) void k_scan3(unsigned int* __restrict__ off,
                                               const unsigned int* __restrict__ bsum,
                                               int N, int E) {
    int i = blockIdx.x * 256 + threadIdx.x;
    if (i < N) off[i] += bsum[blockIdx.x];
    if (i == 0) off[N] = (unsigned int)E;
}

// ---- atomic-free counting-sort fill: csr_src[off[dst]+rank] = src ----
__global__ __launch_bounds__(256) void k_fill(const int* __restrict__ src,
                                              const int* __restrict__ dst,
                                              const unsigned int* __restrict__ off,
                                              const unsigned int* __restrict__ rank,
                                              int* __restrict__ csr_src, int E) {
    int e = blockIdx.x * 256 + threadIdx.x;
    if (e >= E) return;
    csr_src[off[dst[e]] + rank[e]] = src[e];
}

// ---- FUSED gather1 + gemm2: per node (2/wave, 32 lanes each):
//   hid = relu(dinv[n]*(Σ_in dinv[s]*h1u[s] + dinv[n]*h1u[n]) + b1)   -> LDS
//   h2s[n] = (hid @ W2) * dinv[n]                                      (bf16)
__global__ __launch_bounds__(256) void k_g1g2(const unsigned int* __restrict__ off,
                                              const int* __restrict__ csr_src,
                                              const unsigned int* __restrict__ h1s, // bf16x2 unscaled
                                              const float* __restrict__ dinv,
                                              const float* __restrict__ b1,
                                              const float* __restrict__ W2,
                                              unsigned short* __restrict__ h2s, int N) {
    __shared__ float w2s[D_HID * D_OUT];     // 10 KB
    __shared__ float hrow[8][D_HID];         // 2 KB
    const int tid = threadIdx.x;
    const float4* W4 = (const float4*)W2;
    float4* w4 = (float4*)w2s;
    for (int i = tid; i < D_HID * D_OUT / 4; i += 256) w4[i] = W4[i];
    __syncthreads();

    const int lane = tid & 63;
    const int half = lane >> 5;
    const int hl   = lane & 31;
    const int slot = (tid >> 6) * 2 + half;   // 0..7
    const int node = blockIdx.x * 8 + slot;
    const bool valid = node < N;

    int start = 0, end = 0;
    float a0 = 0.0f, a1 = 0.0f;
    float dn = 0.0f;
    if (valid) {
        start = (int)off[node];
        end   = (int)off[node + 1];
        dn = dinv[node];
        unsigned int u = h1s[(size_t)node * 32 + hl];
        a0 = dn * bflo(u);
        a1 = dn * bfhi(u);
    }
    for (int base = start; base < end; base += 32) {
        const int nb = min(32, end - base);
        int sv = (base + hl < end) ? csr_src[base + hl] : 0;
        int j = 0;
        for (; j + 3 < nb; j += 4) {
            int s0 = __shfl(sv, j, 32),     s1 = __shfl(sv, j + 1, 32);
            int s2 = __shfl(sv, j + 2, 32), s3 = __shfl(sv, j + 3, 32);
            unsigned int u0 = h1s[(size_t)s0 * 32 + hl]; float d0 = dinv[s0];
            unsigned int u1 = h1s[(size_t)s1 * 32 + hl]; float d1 = dinv[s1];
            unsigned int u2 = h1s[(size_t)s2 * 32 + hl]; float d2 = dinv[s2];
            unsigned int u3 = h1s[(size_t)s3 * 32 + hl]; float d3 = dinv[s3];
            a0 = fmaf(d0, bflo(u0), a0); a1 = fmaf(d0, bfhi(u0), a1);
            a0 = fmaf(d1, bflo(u1), a0); a1 = fmaf(d1, bfhi(u1), a1);
            a0 = fmaf(d2, bflo(u2), a0); a1 = fmaf(d2, bfhi(u2), a1);
            a0 = fmaf(d3, bflo(u3), a0); a1 = fmaf(d3, bfhi(u3), a1);
        }
        for (; j < nb; ++j) {
            int s = __shfl(sv, j, 32);
            unsigned int uu = h1s[(size_t)s * 32 + hl];
            float dd = dinv[s];
            a0 = fmaf(dd, bflo(uu), a0);
            a1 = fmaf(dd, bfhi(uu), a1);
        }
    }
    if (valid) {
        const float2 bb = *(const float2*)&b1[hl * 2];
        float v0 = fmaf(dn, a0, bb.x);
        float v1 = fmaf(dn, a1, bb.y);
        hrow[slot][hl * 2]     = v0 > 0.0f ? v0 : 0.0f;
        hrow[slot][hl * 2 + 1] = v1 > 0.0f ? v1 : 0.0f;
    }
    __syncthreads();
    // gemm2 epilogue: 20 active lanes per node, 2 cols each
    if (valid && hl < 20) {
        const int c2 = hl * 2;
        float s0 = 0.0f, s1 = 0.0f;
#pragma unroll 8
        for (int k = 0; k < D_HID; ++k) {
            float  xv = hrow[slot][k];                    // broadcast
            float2 wv = *(const float2*)&w2s[k * D_OUT + c2];
            s0 = fmaf(xv, wv.x, s0);
            s1 = fmaf(xv, wv.y, s1);
        }
        unsigned int o = (unsigned)f2bf(s0 * dn) | ((unsigned)f2bf(s1 * dn) << 16);
        *(unsigned int*)&h2s[(size_t)node * D_OUT + c2] = o;
    }
}

// ---- gather2: out[n] = dinv[n]*(Σ_in h2s[src] + h2s[n]) + b2   [fp32 out] ----
__global__ __launch_bounds__(256) void k_gather2(const unsigned int* __restrict__ off,
                                                 const int* __restrict__ csr_src,
                                                 const unsigned int* __restrict__ h2s, // bf16x2
                                                 const float* __restrict__ dinv,
                                                 const float* __restrict__ b2,
                                                 float* __restrict__ out, int N) {
    const int gtid = blockIdx.x * 256 + threadIdx.x;
    const int wid2 = gtid >> 6;
    const int lane = threadIdx.x & 63;
    const int half = lane >> 5;
    const int hl   = lane & 31;
    const int node = wid2 * 2 + half;
    if (node >= N) return;
    const int start = (int)off[node];
    const int end   = (int)off[node + 1];
    const bool act = hl < 20;
    float a0 = 0.0f, a1 = 0.0f;
    if (act) {
        unsigned int u = h2s[(size_t)node * 20 + hl];
        a0 = bflo(u); a1 = bfhi(u);
    }
    for (int base = start; base < end; base += 32) {
        const int nb = min(32, end - base);
        int sv = (base + hl < end) ? csr_src[base + hl] : 0;
        int j = 0;
        for (; j + 3 < nb; j += 4) {
            int s0 = __shfl(sv, j, 32),     s1 = __shfl(sv, j + 1, 32);
            int s2 = __shfl(sv, j + 2, 32), s3 = __shfl(sv, j + 3, 32);
            if (act) {
                unsigned int u0 = h2s[(size_t)s0 * 20 + hl];
                unsigned int u1 = h2s[(size_t)s1 * 20 + hl];
                unsigned int u2 = h2s[(size_t)s2 * 20 + hl];
                unsigned int u3 = h2s[(size_t)s3 * 20 + hl];
                a0 += (bflo(u0) + bflo(u1)) + (bflo(u2) + bflo(u3));
                a1 += (bfhi(u0) + bfhi(u1)) + (bfhi(u2) + bfhi(u3));
            }
        }
        for (; j < nb; ++j) {
            int s = __shfl(sv, j, 32);
            if (act) {
                unsigned int uu = h2s[(size_t)s * 20 + hl];
                a0 += bflo(uu);
                a1 += bfhi(uu);
            }
        }
    }
    if (act) {
        const float dv = dinv[node];
        const float2 bb = *(const float2*)&b2[hl * 2];
        float2 o = {fmaf(dv, a0, bb.x), fmaf(dv, a1, bb.y)};
        *(float2*)&out[(size_t)node * D_OUT + hl * 2] = o;
    }
}

extern "C" void kernel_launch(void* const* d_in, const int* in_sizes, int n_in,
                              void* d_out, int out_size, void* d_ws, size_t ws_size,
                              hipStream_t stream) {
    const float* x  = (const float*)d_in[0];
    const int*  eix = (const int*)d_in[1];   // [2, E] int32 per harness contract
    const float* W1 = (const float*)d_in[2];
    const float* b1 = (const float*)d_in[3];
    const float* W2 = (const float*)d_in[4];
    const float* b2 = (const float*)d_in[5];
    float* out = (float*)d_out;

    const int N = in_sizes[0] / D_IN;
    const int E = in_sizes[1] / 2;
    const int* src = eix;
    const int* dst = eix + E;
    const int NB = (N + 255) / 256;   // scan blocks (<=512 required by k_scan2)

    // ws: deg | dinv | offsets(N+1) | bsums(512) | csr_src(E) | h1s(bf16) | h2s(bf16)
    // rank aliases h2s (rank dead after fill; h2s first written in k_g1g2, after fill).
    char* ws = (char*)d_ws;
    size_t off_b = 0;
    auto alloc = [&](size_t bytes) {
        void* p = ws + off_b;
        off_b = (off_b + bytes + 255) & ~(size_t)255;
        return p;
    };
    unsigned int*   deg     = (unsigned int*)alloc((size_t)N * 4);
    float*          dinv    = (float*)alloc((size_t)N * 4);
    unsigned int*   offsets = (unsigned int*)alloc((size_t)(N + 1) * 4);
    unsigned int*   bsums   = (unsigned int*)alloc(512 * 4);
    int*            csr_src = (int*)alloc((size_t)E * 4);
    unsigned short* h1s     = (unsigned short*)alloc((size_t)N * D_HID * 2);
    unsigned short* h2s     = (unsigned short*)alloc((size_t)E >= (size_t)N * D_OUT / 2
                                                     ? (size_t)E * 4 : (size_t)N * D_OUT * 2);
    unsigned int*   rank    = (unsigned int*)h2s;     // alias: rank dead before h2s written

    hipMemsetAsync(deg, 0, (size_t)N * 4, stream);

    const int DB = (E + 255) / 256;                  // deg-role blocks
    const int GB = (N + 15) / 16;                    // gemm1-role blocks

    // fused deg + gemm1 (unscaled h1s)
    k_deg_g1<<<DB + GB, 256, 0, stream>>>(dst, deg, rank, E, DB, x, W1, h1s, N);

    // CSR scans + fill
    k_scan1<<<NB, 256, 0, stream>>>(deg, offsets, bsums, dinv, N);
    k_scan2<<<1, 512, 0, stream>>>(bsums, NB);
    k_scan3<<<NB, 256, 0, stream>>>(offsets, bsums, N, E);
    k_fill <<<(E + 255) / 256, 256, 0, stream>>>(src, dst, offsets, rank, csr_src, E);

    // fused gather1 + gemm2 (8 nodes/block), then gather2
    k_g1g2  <<<(N + 7) / 8, 256, 0, stream>>>(offsets, csr_src, (const unsigned int*)h1s,
                                              dinv, b1, W2, h2s, N);
    const int gwaves = (N + 1) / 2;
    const int gblocks = (gwaves + 3) / 4;
    k_gather2<<<gblocks, 256, 0, stream>>>(offsets, csr_src, (const unsigned int*)h2s,
                                           dinv, b2, out, N);
}